// Round 1
// baseline (2124.473 us; speedup 1.0000x reference)
//
#include <hip/hip_runtime.h>

#define T_STEPS 64
#define BATCH   256
#define IN_SZ   1024
#define HID     4096
#define BLK     512
#define GATES   12288   // 3*HID
#define GROW    1536    // 3*BLK, rows per diagonal block

#define BM 128
#define BN 128
#define BK 64

// fused step tile
#define BMT 64          // batch rows per workgroup
#define CN  64          // hidden cols per workgroup (64 | 1536 -> no block crossing)

using bf16x8  = __attribute__((ext_vector_type(8))) __bf16;
using floatx4 = __attribute__((ext_vector_type(4))) float;
typedef const __attribute__((address_space(1))) unsigned int* gas_u32;
typedef __attribute__((address_space(3))) unsigned int* las_u32;

__device__ __forceinline__ unsigned short f2bf(float f) {
    union { float f; unsigned int u; } v; v.f = f;
    unsigned int u = v.u;
    unsigned int r = (u + 0x7fffu + ((u >> 16) & 1u)) >> 16;
    return (unsigned short)r;
}

// ---- fp32 -> bf16 cast (vectorized x4) ----
__global__ __launch_bounds__(256) void cast_f32_bf16(
    const float* __restrict__ in, unsigned short* __restrict__ out, int n4)
{
    int i = blockIdx.x * 256 + threadIdx.x;
    if (i >= n4) return;
    float4 v = reinterpret_cast<const float4*>(in)[i];
    ushort4 o;
    o.x = f2bf(v.x); o.y = f2bf(v.y); o.z = f2bf(v.z); o.w = f2bf(v.w);
    reinterpret_cast<ushort4*>(out)[i] = o;
}

// ---- init h state (fp32 in d_out's h_T region) + bf16 copy ----
__global__ __launch_bounds__(256) void init_h(
    const float* __restrict__ h0, float* __restrict__ hT,
    unsigned short* __restrict__ hbf, int n)
{
    int i = blockIdx.x * 256 + threadIdx.x;
    if (i >= n) return;
    float v = h0[i];
    hT[i] = v;
    hbf[i] = f2bf(v);
}

// ---- m97-style GEMM: C(M,GATES) = A(M,K-slice) . B(GATES,K)^T ----
// Used only for the hoisted x-projection now.
__global__ __launch_bounds__(256, 2) void gemm_abt(
    const unsigned short* __restrict__ Ag,
    const unsigned short* __restrict__ Bg,
    float* __restrict__ C,
    int lda, int K, int nt_count, int blockdiag)
{
    __shared__ unsigned short lsA[BM * BK];
    __shared__ unsigned short lsB[BN * BK];

    const int bx = blockIdx.x;
    const int mt = bx / nt_count;
    const int nt = bx - mt * nt_count;
    const int m0 = mt * BM;
    const int n0 = nt * BN;

    const int tid  = threadIdx.x;
    const int wave = tid >> 6;
    const int lane = tid & 63;
    const int q    = lane >> 4;
    const int l16  = lane & 15;
    const int wm   = (wave >> 1) * 64;
    const int wn   = (wave & 1) * 64;

    const int a_col0 = blockdiag ? (n0 / GROW) * BLK : 0;

    floatx4 acc[4][4];
    #pragma unroll
    for (int mf = 0; mf < 4; mf++)
        #pragma unroll
        for (int nf = 0; nf < 4; nf++)
            acc[mf][nf] = floatx4{0.0f, 0.0f, 0.0f, 0.0f};

    for (int k0 = 0; k0 < K; k0 += BK) {
        __syncthreads();
        #pragma unroll
        for (int i = 0; i < 4; i++) {
            const int seg = wave * 4 + i;
            const int g   = seg * 64 + lane;
            const int row = g >> 3;
            const int cs  = ((g & 7) ^ (row & 7)) << 3;
            const unsigned short* ga = Ag + (size_t)(m0 + row) * lda + a_col0 + k0 + cs;
            __builtin_amdgcn_global_load_lds((gas_u32)ga,
                (las_u32)&lsA[seg * 512 + lane * 8], 16, 0, 0);
            const unsigned short* gb = Bg + (size_t)(n0 + row) * (size_t)K + k0 + cs;
            __builtin_amdgcn_global_load_lds((gas_u32)gb,
                (las_u32)&lsB[seg * 512 + lane * 8], 16, 0, 0);
        }
        __syncthreads();

        #pragma unroll
        for (int ks = 0; ks < BK; ks += 32) {
            bf16x8 a[4], b[4];
            #pragma unroll
            for (int mf = 0; mf < 4; mf++) {
                const int row = wm + mf * 16 + l16;
                const int pb  = ((ks >> 3) + q) ^ (row & 7);
                a[mf] = *reinterpret_cast<const bf16x8*>(&lsA[row * BK + pb * 8]);
            }
            #pragma unroll
            for (int nf = 0; nf < 4; nf++) {
                const int row = wn + nf * 16 + l16;
                const int pb  = ((ks >> 3) + q) ^ (row & 7);
                b[nf] = *reinterpret_cast<const bf16x8*>(&lsB[row * BK + pb * 8]);
            }
            #pragma unroll
            for (int mf = 0; mf < 4; mf++)
                #pragma unroll
                for (int nf = 0; nf < 4; nf++)
                    acc[mf][nf] = __builtin_amdgcn_mfma_f32_16x16x32_bf16(
                        a[mf], b[nf], acc[mf][nf], 0, 0, 0);
        }
    }

    #pragma unroll
    for (int mf = 0; mf < 4; mf++) {
        const int mrow0 = m0 + wm + mf * 16 + q * 4;
        #pragma unroll
        for (int nf = 0; nf < 4; nf++) {
            const int col = n0 + wn + nf * 16 + l16;
            #pragma unroll
            for (int r = 0; r < 4; r++)
                C[(size_t)(mrow0 + r) * GATES + col] = acc[mf][nf][r];
        }
    }
}

// ---- fused per-step kernel: block-diag h-GEMM (3 gates) + GRU pointwise ----
// Workgroup = (64 batch rows) x (64 hidden cols). Gate tile of 64 rows never
// crosses a 1536 block boundary, so each gate has ONE h-block (K=512).
// Full-K staging: lsA 64x512 (64 KB) + lsB 64x512 (64 KB) = 128 KB LDS.
// Swizzle: 16B chunk at row-pos p holds logical chunk p^(row&7).
// h ping-pong: read hbf_in, write hbf_out (cross-wg race avoidance).
__global__ __launch_bounds__(256) void fused_step(
    const unsigned short* __restrict__ hbf_in,   // (256,4096) bf16
    const unsigned short* __restrict__ Whb,      // (12288,512) bf16
    const float* __restrict__ xg,                // (256,12288) f32 step slice
    const float* __restrict__ wib,               // (12288,)
    const float* __restrict__ bh,                // (12288,)
    float* __restrict__ hT,                      // (256,4096) f32 live state
    float* __restrict__ out,                     // (256,4096) step output
    unsigned short* __restrict__ hbf_out)        // (256,4096) bf16
{
    __shared__ unsigned short lsA[BMT * BLK];   // 64 KB
    __shared__ unsigned short lsB[CN * BLK];    // 64 KB

    const int bid  = blockIdx.x;
    const int cidx = bid & 63;          // hidden tile (HID/CN = 64)
    const int bidx = bid >> 6;          // batch tile
    const int b0   = bidx * BMT;
    const int c0   = cidx * CN;

    const int tid  = threadIdx.x;
    const int lane = tid & 63;
    const int wave = tid >> 6;
    const int q    = lane >> 4;
    const int l16  = lane & 15;
    const int wm   = (wave >> 1) * 32;  // 2x2 wave quadrants of 32x32
    const int wn   = (wave & 1) * 32;

    floatx4 accR[2][2], accZ[2][2], accN[2][2];
    #pragma unroll
    for (int mf = 0; mf < 2; mf++)
        #pragma unroll
        for (int nf = 0; nf < 2; nf++) {
            accR[mf][nf] = floatx4{0.f, 0.f, 0.f, 0.f};
            accZ[mf][nf] = floatx4{0.f, 0.f, 0.f, 0.f};
            accN[mf][nf] = floatx4{0.f, 0.f, 0.f, 0.f};
        }

    // One gate: stage A(h-block slice) + B(weight rows) full-K, then 16 MFMA steps.
    #define GATE_BODY(G, ACC)                                                        \
    {                                                                                \
        const int gbase = (G) * HID;                                                 \
        const int nb    = (gbase + c0) / GROW;                                       \
        const int acol0 = nb * BLK;                                                  \
        const unsigned short* Bbase = Whb + (size_t)(gbase + c0) * BLK;              \
        __syncthreads();  /* prior gate's LDS reads complete before overwrite */     \
        _Pragma("unroll")                                                            \
        for (int it = 0; it < 16; it++) {                                            \
            const int gc  = it * 256 + tid;                                          \
            const int row = gc >> 6;                                                 \
            const int kb  = (gc & 63) ^ (row & 7);                                   \
            const unsigned short* ga =                                               \
                hbf_in + (size_t)(b0 + row) * HID + acol0 + kb * 8;                  \
            __builtin_amdgcn_global_load_lds((gas_u32)ga,                            \
                (las_u32)&lsA[gc * 8], 16, 0, 0);                                    \
            const unsigned short* gb = Bbase + (size_t)row * BLK + kb * 8;           \
            __builtin_amdgcn_global_load_lds((gas_u32)gb,                            \
                (las_u32)&lsB[gc * 8], 16, 0, 0);                                    \
        }                                                                            \
        __syncthreads();  /* compiler drains vmcnt(0) before barrier */              \
        _Pragma("unroll")                                                            \
        for (int ks = 0; ks < BLK; ks += 32) {                                       \
            bf16x8 a[2], b[2];                                                       \
            _Pragma("unroll")                                                        \
            for (int mf = 0; mf < 2; mf++) {                                         \
                const int row = wm + mf * 16 + l16;                                  \
                const int pb  = ((ks >> 3) + q) ^ (row & 7);                         \
                a[mf] = *reinterpret_cast<const bf16x8*>(&lsA[row * BLK + pb * 8]);  \
            }                                                                        \
            _Pragma("unroll")                                                        \
            for (int nf = 0; nf < 2; nf++) {                                         \
                const int row = wn + nf * 16 + l16;                                  \
                const int pb  = ((ks >> 3) + q) ^ (row & 7);                         \
                b[nf] = *reinterpret_cast<const bf16x8*>(&lsB[row * BLK + pb * 8]);  \
            }                                                                        \
            _Pragma("unroll")                                                        \
            for (int mf = 0; mf < 2; mf++)                                           \
                _Pragma("unroll")                                                    \
                for (int nf = 0; nf < 2; nf++)                                       \
                    ACC[mf][nf] = __builtin_amdgcn_mfma_f32_16x16x32_bf16(           \
                        a[mf], b[nf], ACC[mf][nf], 0, 0, 0);                         \
        }                                                                            \
    }

    GATE_BODY(0, accR)
    GATE_BODY(1, accZ)
    GATE_BODY(2, accN)
    #undef GATE_BODY

    // ---- pointwise epilogue, all in registers; acc layouts element-aligned ----
    #pragma unroll
    for (int nf = 0; nf < 2; nf++) {
        const int i   = c0 + wn + nf * 16 + l16;       // hidden col
        const float br  = wib[i] + bh[i];
        const float bz  = wib[HID + i] + bh[HID + i];
        const float bxn = wib[2 * HID + i];
        const float bhn = bh[2 * HID + i];
        #pragma unroll
        for (int mf = 0; mf < 2; mf++) {
            const int m0r = b0 + wm + mf * 16 + q * 4;  // batch row base
            #pragma unroll
            for (int r = 0; r < 4; r++) {
                const int m = m0r + r;
                const size_t xb = (size_t)m * GATES;
                const float gr = xg[xb + i]           + br  + accR[mf][nf][r];
                const float gz = xg[xb + HID + i]     + bz  + accZ[mf][nf][r];
                const float xn = xg[xb + 2 * HID + i] + bxn;
                const float hn = accN[mf][nf][r]      + bhn;
                const float rr = 1.0f / (1.0f + __expf(-gr));
                const float zz = 1.0f / (1.0f + __expf(-gz));
                const float nn = tanhf(xn + rr * hn);
                const size_t hi = (size_t)m * HID + i;
                const float ho = hT[hi];
                const float hnew = (1.0f - zz) * nn + zz * ho;
                hT[hi]      = hnew;
                out[hi]     = hnew;
                hbf_out[hi] = f2bf(hnew);
            }
        }
    }
}

extern "C" void kernel_launch(void* const* d_in, const int* in_sizes, int n_in,
                              void* d_out, int out_size, void* d_ws, size_t ws_size,
                              hipStream_t stream)
{
    const float* x   = (const float*)d_in[0];   // (64,256,1024)
    const float* h0  = (const float*)d_in[1];   // (256,4096)
    const float* Wi  = (const float*)d_in[2];   // (12288,1024)
    const float* Wib = (const float*)d_in[3];   // (12288,)
    const float* Wh  = (const float*)d_in[4];   // (8,1536,512)
    const float* bh  = (const float*)d_in[5];   // (12288,)

    float* out = (float*)d_out;                          // (64,256,4096)
    float* hT  = out + (size_t)T_STEPS * BATCH * HID;    // (256,4096) — live h state

    // workspace layout (~840 MiB)
    float* xg_all        = (float*)d_ws;                                   // 64*256*12288 f32 (805 MB)
    unsigned short* x_bf = (unsigned short*)(xg_all + (size_t)T_STEPS * BATCH * GATES);
    unsigned short* wi_bf = x_bf  + (size_t)T_STEPS * BATCH * IN_SZ;       // 12288*1024
    unsigned short* wh_bf = wi_bf + (size_t)GATES * IN_SZ;                 // 12288*512
    unsigned short* hbf0  = wh_bf + (size_t)GATES * BLK;                   // 256*4096 ping
    unsigned short* hbf1  = hbf0  + (size_t)BATCH * HID;                   // 256*4096 pong

    const int n_x  = T_STEPS * BATCH * IN_SZ;   // 16,777,216
    const int n_wi = GATES * IN_SZ;             // 12,582,912
    const int n_wh = GATES * BLK;               //  6,291,456

    cast_f32_bf16<<<(n_x / 4 + 255) / 256, 256, 0, stream>>>(x,  x_bf,  n_x / 4);
    cast_f32_bf16<<<(n_wi / 4 + 255) / 256, 256, 0, stream>>>(Wi, wi_bf, n_wi / 4);
    cast_f32_bf16<<<(n_wh / 4 + 255) / 256, 256, 0, stream>>>(Wh, wh_bf, n_wh / 4);
    init_h<<<(BATCH * HID + 255) / 256, 256, 0, stream>>>(h0, hT, hbf0, BATCH * HID);

    // Hoisted x-projection: (16384 x 1024) . (12288 x 1024)^T -> (16384 x 12288)
    gemm_abt<<<(T_STEPS * BATCH / BM) * (GATES / BN), 256, 0, stream>>>(
        x_bf, wi_bf, xg_all, IN_SZ, IN_SZ, GATES / BN, 0);

    for (int t = 0; t < T_STEPS; t++) {
        fused_step<<<(BATCH / BMT) * (HID / CN), 256, 0, stream>>>(
            (t & 1) ? hbf1 : hbf0, wh_bf,
            xg_all + (size_t)t * BATCH * GATES, Wib, bh,
            hT, out + (size_t)t * BATCH * HID,
            (t & 1) ? hbf0 : hbf1);
    }
}